// Round 3
// baseline (80.807 us; speedup 1.0000x reference)
//
#include <hip/hip_runtime.h>

#define NPTS 32768
#define C 128
#define H 4
#define D 32
#define KNBR 16

typedef __attribute__((ext_vector_type(8))) short short8;
typedef __attribute__((ext_vector_type(4))) float floatx4;
typedef __attribute__((ext_vector_type(4))) int intx4;

__device__ __forceinline__ ushort f2b(float f) {
    union { float f; uint u; } x; x.f = f;
    uint r = (x.u + 0x7fffu + ((x.u >> 16) & 1u)) >> 16;
    return (ushort)r;
}
__device__ __forceinline__ float lo2f(uint u) { union { uint i; float f; } x; x.i = u << 16; return x.f; }
__device__ __forceinline__ float hi2f(uint u) { union { uint i; float f; } x; x.i = u & 0xffff0000u; return x.f; }

// channel c -> storage slot sigma(c) = (c&64) + (c&15)*4 + ((c&63)>>4)
// slot s -> channel col(s) = (s&64) + 16*(s&3) + ((s&63)>>2)
__device__ __forceinline__ int slot2col(int s) {
    return (s & 64) + 16 * (s & 3) + ((s & 63) >> 2);
}

// ---------------- cast fp32 -> bf16 (feats + weights; Wo gets K-permuted) ----------------
__global__ __launch_bounds__(256) void cast_all(
    const float* __restrict__ feats, const float* __restrict__ Wq,
    const float* __restrict__ Wk, const float* __restrict__ Wv,
    const float* __restrict__ Wo,
    ushort* __restrict__ feats_b, ushort* __restrict__ wq_b,
    ushort* __restrict__ wk_b, ushort* __restrict__ wv_b, ushort* __restrict__ wo_b)
{
    const int b = blockIdx.x, tid = threadIdx.x;
    if (b < 2048 + 24) {
        const float* src; ushort* dst; size_t base;
        if (b < 2048) { src = feats; dst = feats_b; base = (size_t)b * 2048; }
        else {
            const int wb = b - 2048, wsel = wb >> 3;
            base = (size_t)(wb & 7) * 2048;
            src = (wsel == 0) ? Wq : (wsel == 1) ? Wk : Wv;
            dst = (wsel == 0) ? wq_b : (wsel == 1) ? wk_b : wv_b;
        }
        const size_t i = base + (size_t)tid * 8;
        float4 v0 = *(const float4*)(src + i);
        float4 v1 = *(const float4*)(src + i + 4);
        uint p0 = (uint)f2b(v0.x) | ((uint)f2b(v0.y) << 16);
        uint p1 = (uint)f2b(v0.z) | ((uint)f2b(v0.w) << 16);
        uint p2 = (uint)f2b(v1.x) | ((uint)f2b(v1.y) << 16);
        uint p3 = (uint)f2b(v1.z) | ((uint)f2b(v1.w) << 16);
        intx4 o; o.x = (int)p0; o.y = (int)p1; o.z = (int)p2; o.w = (int)p3;
        *(intx4*)(dst + i) = o;
    } else {
        // Wo with permuted K axis: wo_b[j*128 + s] = bf16(Wo[j*128 + col(s)])
        const int wb = b - 2072;                    // 0..7
        const size_t base = (size_t)wb * 2048;
        const size_t i = base + (size_t)tid * 8;    // output slot index
        ushort tmp[8];
#pragma unroll
        for (int t = 0; t < 8; ++t) {
            const int gi = (int)(i + t);
            const int j = gi >> 7, s = gi & 127;
            tmp[t] = f2b(Wo[(size_t)j * 128 + slot2col(s)]);
        }
        intx4 o;
        o.x = (int)((uint)tmp[0] | ((uint)tmp[1] << 16));
        o.y = (int)((uint)tmp[2] | ((uint)tmp[3] << 16));
        o.z = (int)((uint)tmp[4] | ((uint)tmp[5] << 16));
        o.w = (int)((uint)tmp[6] | ((uint)tmp[7] << 16));
        *(intx4*)(wo_b + i) = o;
    }
}

// ---------------- MFMA GEMM core: 128x128 tile, K=128, out = A @ W^T ----------------
__device__ __forceinline__ void stage128(const ushort* __restrict__ gsrc, ushort* lds, int tid)
{
#pragma unroll
    for (int it = 0; it < 8; ++it) {
        const int f = it * 256 + tid;
        const int row = f >> 4, slot = f & 15;
        intx4 v = *(const intx4*)(gsrc + (size_t)f * 8);
        *(intx4*)(lds + ((row * 16 + (slot ^ (row & 7))) * 8)) = v;
    }
}

__device__ __forceinline__ void gemm_frag_acc(const ushort* ldsA, const ushort* ldsW,
                                              floatx4 acc[4][4], int lane)
{
    const int fr = lane & 15, kb = lane >> 4;
#pragma unroll
    for (int kk = 0; kk < 4; ++kk) {
        const int slot = kk * 4 + kb;
        short8 af[4], bf[4];
#pragma unroll
        for (int i = 0; i < 4; ++i) {
            const int row = i * 16 + fr;
            af[i] = *(const short8*)(ldsA + ((row * 16 + (slot ^ (row & 7))) * 8));
            bf[i] = *(const short8*)(ldsW + ((row * 16 + (slot ^ (row & 7))) * 8));
        }
#pragma unroll
        for (int i = 0; i < 4; ++i)
#pragma unroll
            for (int j = 0; j < 4; ++j)
                acc[i][j] = __builtin_amdgcn_mfma_f32_16x16x32_bf16(af[i], bf[j], acc[i][j], 0, 0, 0);
    }
}

// QKV fused. sel=0: q_perm bf16 (permuted). sel=1: k int8 -> kv8[n][0:128]. sel=2: v int8 -> kv8[n][128:256].
__global__ __launch_bounds__(256) void qkv_gemm(
    const ushort* __restrict__ A, const ushort* __restrict__ Wq_b,
    const ushort* __restrict__ Wk_b, const ushort* __restrict__ Wv_b,
    ushort* __restrict__ q_perm, unsigned char* __restrict__ kv8,
    float* __restrict__ scales)
{
    __shared__ ushort ldsA[16384];
    __shared__ ushort ldsW[16384];
    __shared__ float rmax[2][128];
    const int tid = threadIdx.x, lane = tid & 63, wid = tid >> 6;
    const int r0 = blockIdx.x * 128, sel = blockIdx.y;
    const ushort* W = (sel == 0) ? Wq_b : (sel == 1) ? Wk_b : Wv_b;

    stage128(A + (size_t)r0 * 128, ldsA, tid);
    stage128(W, ldsW, tid);
    __syncthreads();

    floatx4 acc[4][4];
#pragma unroll
    for (int i = 0; i < 4; ++i)
#pragma unroll
        for (int j = 0; j < 4; ++j) acc[i][j] = (floatx4){0.f, 0.f, 0.f, 0.f};

    const int wr = (wid >> 1) * 64, wc = (wid & 1) * 64;
    gemm_frag_acc(ldsA + wr * 16 * 8, ldsW + wc * 16 * 8, acc, lane);

    const int fr = lane & 15, kb = lane >> 4;

    if (sel == 0) {
        // q: store bf16 in permuted layout; per (i,r): slots wc+fr*4+{0..3} contiguous
#pragma unroll
        for (int i = 0; i < 4; ++i)
#pragma unroll
            for (int r = 0; r < 4; ++r) {
                const int n = r0 + wr + i * 16 + kb * 4 + r;
                uint lo = (uint)f2b(acc[i][0][r]) | ((uint)f2b(acc[i][1][r]) << 16);
                uint hi = (uint)f2b(acc[i][2][r]) | ((uint)f2b(acc[i][3][r]) << 16);
                uint2 o; o.x = lo; o.y = hi;
                *(uint2*)(q_perm + (size_t)n * 128 + wc + fr * 4) = o;
            }
    } else {
        // per-row absmax over this wave's 64 cols
        float mx[4][4];
#pragma unroll
        for (int i = 0; i < 4; ++i)
#pragma unroll
            for (int r = 0; r < 4; ++r) {
                float m = fabsf(acc[i][0][r]);
                m = fmaxf(m, fabsf(acc[i][1][r]));
                m = fmaxf(m, fabsf(acc[i][2][r]));
                m = fmaxf(m, fabsf(acc[i][3][r]));
                m = fmaxf(m, __shfl_xor(m, 1));
                m = fmaxf(m, __shfl_xor(m, 2));
                m = fmaxf(m, __shfl_xor(m, 4));
                m = fmaxf(m, __shfl_xor(m, 8));
                mx[i][r] = m;
            }
        if (fr == 0) {
#pragma unroll
            for (int i = 0; i < 4; ++i)
#pragma unroll
                for (int r = 0; r < 4; ++r)
                    rmax[wc >> 6][wr + i * 16 + kb * 4 + r] = mx[i][r];
        }
        __syncthreads();
        const int half = (sel == 2) ? 128 : 0;
#pragma unroll
        for (int i = 0; i < 4; ++i)
#pragma unroll
            for (int r = 0; r < 4; ++r) {
                const int lr = wr + i * 16 + kb * 4 + r;
                const int n = r0 + lr;
                const float comb = fmaxf(fmaxf(rmax[0][lr], rmax[1][lr]), 1e-20f);
                if (fr == 0 && wc == 0)
                    scales[(size_t)n * 2 + (sel - 1)] = comb * (1.f / 127.f);
                const float qs = 127.f / comb;
                int b0 = __float2int_rn(acc[i][0][r] * qs);
                int b1 = __float2int_rn(acc[i][1][r] * qs);
                int b2 = __float2int_rn(acc[i][2][r] * qs);
                int b3 = __float2int_rn(acc[i][3][r] * qs);
                uint w = (uint)(b0 & 0xff) | ((uint)(b1 & 0xff) << 8) |
                         ((uint)(b2 & 0xff) << 16) | ((uint)(b3 & 0xff) << 24);
                *(uint*)(kv8 + (size_t)n * 256 + half + wc + fr * 4) = w;
            }
    }
}

// ---------------- attention with int8 kv ----------------
// lane l: slots 2l,2l+1 -> channels c_lo, c_lo+16 of head h = 2*(l>>5)+(l&1)
// head group = 16 lanes stride 2 -> reduce with shfl_xor {2,4,8,16}
__global__ __launch_bounds__(256) void attn_kernel(
    const ushort* __restrict__ q_perm, const unsigned char* __restrict__ kv8,
    const float* __restrict__ scales, const int* __restrict__ knn,
    ushort* __restrict__ attn_perm)
{
    const int tid = threadIdx.x;
    const int lane = tid & 63;
    const int n = blockIdx.x * 4 + (tid >> 6);

    const uint q2 = *(const uint*)(q_perm + (size_t)n * 128 + 2 * lane);
    const float q0 = lo2f(q2), q1 = hi2f(q2);

    int nb[KNBR];
    {
        intx4 a = *(const intx4*)(knn + (size_t)n * KNBR);
        intx4 b = *(const intx4*)(knn + (size_t)n * KNBR + 4);
        intx4 c = *(const intx4*)(knn + (size_t)n * KNBR + 8);
        intx4 d = *(const intx4*)(knn + (size_t)n * KNBR + 12);
        nb[0]=a.x; nb[1]=a.y; nb[2]=a.z; nb[3]=a.w;
        nb[4]=b.x; nb[5]=b.y; nb[6]=b.z; nb[7]=b.w;
        nb[8]=c.x; nb[9]=c.y; nb[10]=c.z; nb[11]=c.w;
        nb[12]=d.x; nb[13]=d.y; nb[14]=d.z; nb[15]=d.w;
    }

    float s[KNBR], vsc[KNBR];
#pragma unroll
    for (int kk = 0; kk < KNBR; ++kk) {
        const size_t rb = (size_t)nb[kk] * 256;
        const ushort k2 = *(const ushort*)(kv8 + rb + 2 * lane);
        const float2 sc = *(const float2*)(scales + (size_t)nb[kk] * 2);
        vsc[kk] = sc.y;
        const float k0 = (float)(signed char)(k2 & 0xff);
        const float k1 = (float)(signed char)(k2 >> 8);
        float p = q0 * k0 + q1 * k1;
        p += __shfl_xor(p, 2);
        p += __shfl_xor(p, 4);
        p += __shfl_xor(p, 8);
        p += __shfl_xor(p, 16);
        s[kk] = p * sc.x * 0.17677669529663687f;   // ksc * 1/sqrt(32)
    }

    float m = s[0];
#pragma unroll
    for (int kk = 1; kk < KNBR; ++kk) m = fmaxf(m, s[kk]);
    float sum = 0.f;
#pragma unroll
    for (int kk = 0; kk < KNBR; ++kk) { s[kk] = __expf(s[kk] - m); sum += s[kk]; }
    const float inv = 1.f / sum;

    float a0 = 0.f, a1 = 0.f;
#pragma unroll
    for (int kk = 0; kk < KNBR; ++kk) {
        const ushort v2 = *(const ushort*)(kv8 + (size_t)nb[kk] * 256 + 128 + 2 * lane);
        const float w = s[kk] * vsc[kk];
        a0 += w * (float)(signed char)(v2 & 0xff);
        a1 += w * (float)(signed char)(v2 >> 8);
    }
    a0 *= inv; a1 *= inv;

    const uint pr = (uint)f2b(a0) | ((uint)f2b(a1) << 16);
    *(uint*)(attn_perm + (size_t)n * 128 + 2 * lane) = pr;
}

// Output projection (permutation-invariant over K since attn_perm and wo_b share sigma)
__global__ __launch_bounds__(256) void out_gemm(
    const ushort* __restrict__ A, const ushort* __restrict__ Wo_b,
    const float* __restrict__ bias, float* __restrict__ out)
{
    __shared__ ushort ldsA[16384];
    __shared__ ushort ldsW[16384];
    const int tid = threadIdx.x, lane = tid & 63, wid = tid >> 6;
    const int r0 = blockIdx.x * 128;

    stage128(A + (size_t)r0 * 128, ldsA, tid);
    stage128(Wo_b, ldsW, tid);
    __syncthreads();

    floatx4 acc[4][4];
#pragma unroll
    for (int i = 0; i < 4; ++i)
#pragma unroll
        for (int j = 0; j < 4; ++j) acc[i][j] = (floatx4){0.f, 0.f, 0.f, 0.f};

    const int wr = (wid >> 1) * 64, wc = (wid & 1) * 64;
    gemm_frag_acc(ldsA + wr * 16 * 8, ldsW + wc * 16 * 8, acc, lane);

    const int fr = lane & 15, kb = lane >> 4;
#pragma unroll
    for (int i = 0; i < 4; ++i)
#pragma unroll
        for (int j = 0; j < 4; ++j) {
            const int col = wc + j * 16 + fr;
            const float bv = bias[col];
#pragma unroll
            for (int r = 0; r < 4; ++r) {
                const int n = r0 + wr + i * 16 + kb * 4 + r;
                out[(size_t)n * 128 + col] = acc[i][j][r] + bv;
            }
        }
}

extern "C" void kernel_launch(void* const* d_in, const int* in_sizes, int n_in,
                              void* d_out, int out_size, void* d_ws, size_t ws_size,
                              hipStream_t stream)
{
    const float* feats = (const float*)d_in[0];
    const int*   knn   = (const int*)d_in[2];
    const float* Wq    = (const float*)d_in[3];
    const float* Wk    = (const float*)d_in[4];
    const float* Wv    = (const float*)d_in[5];
    const float* Wo    = (const float*)d_in[6];
    const float* bo    = (const float*)d_in[7];
    float* out = (float*)d_out;

    ushort* ws = (ushort*)d_ws;
    ushort* feats_b  = ws;                                   // N*128 ushort
    ushort* q_perm   = feats_b  + (size_t)NPTS * C;          // N*128 ushort
    ushort* attn_p   = q_perm   + (size_t)NPTS * C;          // N*128 ushort
    unsigned char* kv8 = (unsigned char*)(attn_p + (size_t)NPTS * C);  // N*256 bytes
    float* scales    = (float*)(kv8 + (size_t)NPTS * 256);   // N*2 float
    ushort* wq_b     = (ushort*)(scales + (size_t)NPTS * 2);
    ushort* wk_b     = wq_b + 16384;
    ushort* wv_b     = wk_b + 16384;
    ushort* wo_b     = wv_b + 16384;

    cast_all<<<2080, 256, 0, stream>>>(feats, Wq, Wk, Wv, Wo,
                                       feats_b, wq_b, wk_b, wv_b, wo_b);
    qkv_gemm<<<dim3(NPTS / 128, 3), 256, 0, stream>>>(feats_b, wq_b, wk_b, wv_b,
                                                      q_perm, kv8, scales);
    attn_kernel<<<NPTS / 4, 256, 0, stream>>>(q_perm, kv8, scales, knn, attn_p);
    out_gemm<<<NPTS / 128, 256, 0, stream>>>(attn_p, wo_b, bo, out);
}

// Round 4
// 62.820 us; speedup vs baseline: 1.2863x; 1.2863x over previous
//
#include <hip/hip_runtime.h>

#define NPTS 32768
#define C 128
#define H 4
#define D 32
#define KNBR 16

typedef __attribute__((ext_vector_type(8))) short short8;
typedef __attribute__((ext_vector_type(4))) float floatx4;
typedef __attribute__((ext_vector_type(4))) int intx4;

__device__ __forceinline__ ushort f2b(float f) {
    union { float f; uint u; } x; x.f = f;
    uint r = (x.u + 0x7fffu + ((x.u >> 16) & 1u)) >> 16;
    return (ushort)r;
}

// Storage permutation for int8 rows: word w (0..31 per 128B half), byte b (0..3)
// holds channel col_of(w,b). Head of word w = w>>3 (head-pure words).
__device__ __forceinline__ int col_of(int w, int b) {
    return 64 * (w >> 4) + 32 * ((w >> 3) & 1) + 16 * (b & 1) + 2 * (w & 7) + (b >> 1);
}

// ---------------- cast fp32 -> bf16 (feats + Wq/Wk/Wv; Wo K-permuted by col_of) ----------------
__global__ __launch_bounds__(256) void cast_all(
    const float* __restrict__ feats, const float* __restrict__ Wq,
    const float* __restrict__ Wk, const float* __restrict__ Wv,
    const float* __restrict__ Wo,
    ushort* __restrict__ feats_b, ushort* __restrict__ wq_b,
    ushort* __restrict__ wk_b, ushort* __restrict__ wv_b, ushort* __restrict__ wo_b)
{
    const int b = blockIdx.x, tid = threadIdx.x;
    if (b < 2048 + 24) {
        const float* src; ushort* dst; size_t base;
        if (b < 2048) { src = feats; dst = feats_b; base = (size_t)b * 2048; }
        else {
            const int wb = b - 2048, wsel = wb >> 3;
            base = (size_t)(wb & 7) * 2048;
            src = (wsel == 0) ? Wq : (wsel == 1) ? Wk : Wv;
            dst = (wsel == 0) ? wq_b : (wsel == 1) ? wk_b : wv_b;
        }
        const size_t i = base + (size_t)tid * 8;
        float4 v0 = *(const float4*)(src + i);
        float4 v1 = *(const float4*)(src + i + 4);
        uint p0 = (uint)f2b(v0.x) | ((uint)f2b(v0.y) << 16);
        uint p1 = (uint)f2b(v0.z) | ((uint)f2b(v0.w) << 16);
        uint p2 = (uint)f2b(v1.x) | ((uint)f2b(v1.y) << 16);
        uint p3 = (uint)f2b(v1.z) | ((uint)f2b(v1.w) << 16);
        intx4 o; o.x = (int)p0; o.y = (int)p1; o.z = (int)p2; o.w = (int)p3;
        *(intx4*)(dst + i) = o;
    } else {
        // wo_b[j*128 + s] = bf16(Wo[j*128 + col_of(s>>2, s&3)])
        const int wb = b - 2072;                    // 0..7
        const size_t base = (size_t)wb * 2048;
        const size_t i = base + (size_t)tid * 8;
        ushort tmp[8];
#pragma unroll
        for (int t = 0; t < 8; ++t) {
            const int gi = (int)(i + t);
            const int j = gi >> 7, s = gi & 127;
            tmp[t] = f2b(Wo[(size_t)j * 128 + col_of(s >> 2, s & 3)]);
        }
        intx4 o;
        o.x = (int)((uint)tmp[0] | ((uint)tmp[1] << 16));
        o.y = (int)((uint)tmp[2] | ((uint)tmp[3] << 16));
        o.z = (int)((uint)tmp[4] | ((uint)tmp[5] << 16));
        o.w = (int)((uint)tmp[6] | ((uint)tmp[7] << 16));
        *(intx4*)(wo_b + i) = o;
    }
}

// ---------------- MFMA GEMM core: 128x128 tile, K=128, out = A @ W^T ----------------
__device__ __forceinline__ void stage128(const ushort* __restrict__ gsrc, ushort* lds, int tid)
{
#pragma unroll
    for (int it = 0; it < 8; ++it) {
        const int f = it * 256 + tid;
        const int row = f >> 4, slot = f & 15;
        intx4 v = *(const intx4*)(gsrc + (size_t)f * 8);
        *(intx4*)(lds + ((row * 16 + (slot ^ (row & 7))) * 8)) = v;
    }
}

__device__ __forceinline__ void gemm_frag_acc(const ushort* ldsA, const ushort* ldsW,
                                              floatx4 acc[4][4], int lane)
{
    const int fr = lane & 15, kb = lane >> 4;
#pragma unroll
    for (int kk = 0; kk < 4; ++kk) {
        const int slot = kk * 4 + kb;
        short8 af[4], bf[4];
#pragma unroll
        for (int i = 0; i < 4; ++i) {
            const int row = i * 16 + fr;
            af[i] = *(const short8*)(ldsA + ((row * 16 + (slot ^ (row & 7))) * 8));
            bf[i] = *(const short8*)(ldsW + ((row * 16 + (slot ^ (row & 7))) * 8));
        }
#pragma unroll
        for (int i = 0; i < 4; ++i)
#pragma unroll
            for (int j = 0; j < 4; ++j)
                acc[i][j] = __builtin_amdgcn_mfma_f32_16x16x32_bf16(af[i], bf[j], acc[i][j], 0, 0, 0);
    }
}

// QKV fused, all three outputs int8 per-row-scaled in col_of permuted layout.
// sel=0 -> q8[n][128]; sel=1 -> kv8[n][0:128] (k); sel=2 -> kv8[n][128:256] (v).
// scales4[n] = {ksc, vsc, qsc, pad}
__global__ __launch_bounds__(256) void qkv_gemm(
    const ushort* __restrict__ A, const ushort* __restrict__ Wq_b,
    const ushort* __restrict__ Wk_b, const ushort* __restrict__ Wv_b,
    unsigned char* __restrict__ q8, unsigned char* __restrict__ kv8,
    float* __restrict__ scales4)
{
    __shared__ ushort ldsA[16384];
    __shared__ ushort ldsW[16384];
    __shared__ float rmax[2][128];
    const int tid = threadIdx.x, lane = tid & 63, wid = tid >> 6;
    const int r0 = blockIdx.x * 128, sel = blockIdx.y;
    const ushort* W = (sel == 0) ? Wq_b : (sel == 1) ? Wk_b : Wv_b;

    stage128(A + (size_t)r0 * 128, ldsA, tid);
    stage128(W, ldsW, tid);
    __syncthreads();

    floatx4 acc[4][4];
#pragma unroll
    for (int i = 0; i < 4; ++i)
#pragma unroll
        for (int j = 0; j < 4; ++j) acc[i][j] = (floatx4){0.f, 0.f, 0.f, 0.f};

    const int wr = (wid >> 1) * 64, wc = (wid & 1) * 64;
    gemm_frag_acc(ldsA + wr * 16 * 8, ldsW + wc * 16 * 8, acc, lane);

    const int fr = lane & 15, kb = lane >> 4;

    // per-(i,r) row absmax over this wave's 64 cols
    float mx[4][4];
#pragma unroll
    for (int i = 0; i < 4; ++i)
#pragma unroll
        for (int r = 0; r < 4; ++r) {
            float m = fabsf(acc[i][0][r]);
            m = fmaxf(m, fabsf(acc[i][1][r]));
            m = fmaxf(m, fabsf(acc[i][2][r]));
            m = fmaxf(m, fabsf(acc[i][3][r]));
            m = fmaxf(m, __shfl_xor(m, 1));
            m = fmaxf(m, __shfl_xor(m, 2));
            m = fmaxf(m, __shfl_xor(m, 4));
            m = fmaxf(m, __shfl_xor(m, 8));
            mx[i][r] = m;
        }
    if (fr == 0) {
#pragma unroll
        for (int i = 0; i < 4; ++i)
#pragma unroll
            for (int r = 0; r < 4; ++r)
                rmax[wc >> 6][wr + i * 16 + kb * 4 + r] = mx[i][r];
    }
    __syncthreads();

    const int scidx = (sel + 2) % 3;   // sel0->2 (qsc), sel1->0 (ksc), sel2->1 (vsc)
    const int boff = ((wc >> 5) + (fr & 1)) * 32 + (fr >> 1) * 4;  // byte offset of this thread's word
#pragma unroll
    for (int i = 0; i < 4; ++i)
#pragma unroll
        for (int r = 0; r < 4; ++r) {
            const int lr = wr + i * 16 + kb * 4 + r;
            const int nn = r0 + lr;
            const float comb = fmaxf(fmaxf(rmax[0][lr], rmax[1][lr]), 1e-20f);
            if (fr == 0 && wc == 0)
                scales4[(size_t)nn * 4 + scidx] = comb * (1.f / 127.f);
            const float qs = 127.f / comb;
            int b0 = __float2int_rn(acc[i][0][r] * qs);
            int b1 = __float2int_rn(acc[i][1][r] * qs);
            int b2 = __float2int_rn(acc[i][2][r] * qs);
            int b3 = __float2int_rn(acc[i][3][r] * qs);
            uint u_lo = (uint)(b0 & 0xff) | ((uint)(b1 & 0xff) << 8);   // j0,j1 (low head)
            uint u_hi = (uint)(b2 & 0xff) | ((uint)(b3 & 0xff) << 8);   // j2,j3 (high head)
            uint o_lo = __shfl_xor(u_lo, 1);
            uint o_hi = __shfl_xor(u_hi, 1);
            uint word = (fr & 1) ? (o_hi | (u_hi << 16)) : (u_lo | (o_lo << 16));
            if (sel == 0)      *(uint*)(q8  + (size_t)nn * 128 + boff) = word;
            else if (sel == 1) *(uint*)(kv8 + (size_t)nn * 256 + boff) = word;
            else               *(uint*)(kv8 + (size_t)nn * 256 + 128 + boff) = word;
        }
}

// ---------------- attention: 1 wave/point, one 256B coalesced load per neighbor ----------------
// lanes 0-31: k words (head = lane>>3); lanes 32-63: v words (head = (lane-32)>>3)
__global__ __launch_bounds__(256) void attn_kernel(
    const unsigned char* __restrict__ q8, const unsigned char* __restrict__ kv8,
    const float* __restrict__ scales4, const int* __restrict__ knn,
    ushort* __restrict__ attn_p)
{
    const int tid = threadIdx.x;
    const int lane = tid & 63;
    const int n = blockIdx.x * 4 + (tid >> 6);

    int nb[KNBR];
    {
        const int* kr = knn + (size_t)n * KNBR;
        intx4 a = *(const intx4*)kr;
        intx4 b = *(const intx4*)(kr + 4);
        intx4 c = *(const intx4*)(kr + 8);
        intx4 d = *(const intx4*)(kr + 12);
        nb[0]  = __builtin_amdgcn_readfirstlane(a.x);
        nb[1]  = __builtin_amdgcn_readfirstlane(a.y);
        nb[2]  = __builtin_amdgcn_readfirstlane(a.z);
        nb[3]  = __builtin_amdgcn_readfirstlane(a.w);
        nb[4]  = __builtin_amdgcn_readfirstlane(b.x);
        nb[5]  = __builtin_amdgcn_readfirstlane(b.y);
        nb[6]  = __builtin_amdgcn_readfirstlane(b.z);
        nb[7]  = __builtin_amdgcn_readfirstlane(b.w);
        nb[8]  = __builtin_amdgcn_readfirstlane(c.x);
        nb[9]  = __builtin_amdgcn_readfirstlane(c.y);
        nb[10] = __builtin_amdgcn_readfirstlane(c.z);
        nb[11] = __builtin_amdgcn_readfirstlane(c.w);
        nb[12] = __builtin_amdgcn_readfirstlane(d.x);
        nb[13] = __builtin_amdgcn_readfirstlane(d.y);
        nb[14] = __builtin_amdgcn_readfirstlane(d.z);
        nb[15] = __builtin_amdgcn_readfirstlane(d.w);
    }

    uint q4 = 0;
    if (lane < 32) q4 = *(const uint*)(q8 + (size_t)n * 128 + lane * 4);
    const float qs6 = scales4[(size_t)n * 4 + 2] * 0.17677669529663687f;  // qsc / sqrt(32)

    // batch-issue all 16 row loads (+scales)
    uint u[KNBR];
    float ks[KNBR], vs[KNBR];
#pragma unroll
    for (int kk = 0; kk < KNBR; ++kk) {
        u[kk] = *(const uint*)(kv8 + (size_t)nb[kk] * 256 + lane * 4);
        const float* sc = scales4 + (size_t)nb[kk] * 4;
        ks[kk] = sc[0];
        vs[kk] = sc[1];
    }

    float s[KNBR];
#pragma unroll
    for (int kk = 0; kk < KNBR; ++kk) {
#if __has_builtin(__builtin_amdgcn_sdot4)
        int dp = __builtin_amdgcn_sdot4((int)q4, (int)u[kk], 0, false);
#else
        int dp = (int)(signed char)(q4)       * (int)(signed char)(u[kk])
               + (int)(signed char)(q4 >> 8)  * (int)(signed char)(u[kk] >> 8)
               + (int)(signed char)(q4 >> 16) * (int)(signed char)(u[kk] >> 16)
               + (int)(signed char)(q4 >> 24) * (int)(signed char)(u[kk] >> 24);
#endif
        float f = (float)dp;
        f += __shfl_xor(f, 1);
        f += __shfl_xor(f, 2);
        f += __shfl_xor(f, 4);
        f += __shfl_xor(f, 32);     // broadcast k-half sums to v-half
        s[kk] = f * ks[kk] * qs6;
    }

    float m = s[0];
#pragma unroll
    for (int kk = 1; kk < KNBR; ++kk) m = fmaxf(m, s[kk]);
    float sum = 0.f;
#pragma unroll
    for (int kk = 0; kk < KNBR; ++kk) { s[kk] = __expf(s[kk] - m); sum += s[kk]; }
    const float inv = 1.f / sum;

    float a0 = 0.f, a1 = 0.f, a2 = 0.f, a3 = 0.f;
#pragma unroll
    for (int kk = 0; kk < KNBR; ++kk) {
        const float wv = s[kk] * vs[kk];
        const uint uu = u[kk];
        a0 += wv * (float)(signed char)(uu);
        a1 += wv * (float)(signed char)(uu >> 8);
        a2 += wv * (float)(signed char)(uu >> 16);
        a3 += wv * (float)(signed char)(uu >> 24);
    }
    a0 *= inv; a1 *= inv; a2 *= inv; a3 *= inv;

    if (lane >= 32) {
        const int x = lane - 32;
        uint2 o;
        o.x = (uint)f2b(a0) | ((uint)f2b(a1) << 16);
        o.y = (uint)f2b(a2) | ((uint)f2b(a3) << 16);
        *(uint2*)(attn_p + (size_t)n * 128 + x * 4) = o;
    }
}

// Output projection: out = attn_p @ wo_b^T + bo (both sides share the col_of K-permutation)
__global__ __launch_bounds__(256) void out_gemm(
    const ushort* __restrict__ A, const ushort* __restrict__ Wo_b,
    const float* __restrict__ bias, float* __restrict__ out)
{
    __shared__ ushort ldsA[16384];
    __shared__ ushort ldsW[16384];
    const int tid = threadIdx.x, lane = tid & 63, wid = tid >> 6;
    const int r0 = blockIdx.x * 128;

    stage128(A + (size_t)r0 * 128, ldsA, tid);
    stage128(Wo_b, ldsW, tid);
    __syncthreads();

    floatx4 acc[4][4];
#pragma unroll
    for (int i = 0; i < 4; ++i)
#pragma unroll
        for (int j = 0; j < 4; ++j) acc[i][j] = (floatx4){0.f, 0.f, 0.f, 0.f};

    const int wr = (wid >> 1) * 64, wc = (wid & 1) * 64;
    gemm_frag_acc(ldsA + wr * 16 * 8, ldsW + wc * 16 * 8, acc, lane);

    const int fr = lane & 15, kb = lane >> 4;
#pragma unroll
    for (int i = 0; i < 4; ++i)
#pragma unroll
        for (int j = 0; j < 4; ++j) {
            const int col = wc + j * 16 + fr;
            const float bv = bias[col];
#pragma unroll
            for (int r = 0; r < 4; ++r) {
                const int n = r0 + wr + i * 16 + kb * 4 + r;
                out[(size_t)n * 128 + col] = acc[i][j][r] + bv;
            }
        }
}

extern "C" void kernel_launch(void* const* d_in, const int* in_sizes, int n_in,
                              void* d_out, int out_size, void* d_ws, size_t ws_size,
                              hipStream_t stream)
{
    const float* feats = (const float*)d_in[0];
    const int*   knn   = (const int*)d_in[2];
    const float* Wq    = (const float*)d_in[3];
    const float* Wk    = (const float*)d_in[4];
    const float* Wv    = (const float*)d_in[5];
    const float* Wo    = (const float*)d_in[6];
    const float* bo    = (const float*)d_in[7];
    float* out = (float*)d_out;

    ushort* feats_b = (ushort*)d_ws;                                   // N*128 ushort
    ushort* attn_p  = feats_b + (size_t)NPTS * C;                      // N*128 ushort
    unsigned char* q8  = (unsigned char*)(attn_p + (size_t)NPTS * C);  // N*128 B (+256 pad)
    unsigned char* kv8 = q8 + (size_t)NPTS * 128 + 256;                // N*256 B
    float* scales4  = (float*)(kv8 + (size_t)NPTS * 256);              // N*4 float
    ushort* wq_b    = (ushort*)(scales4 + (size_t)NPTS * 4);
    ushort* wk_b    = wq_b + 16384;
    ushort* wv_b    = wk_b + 16384;
    ushort* wo_b    = wv_b + 16384;

    cast_all<<<2080, 256, 0, stream>>>(feats, Wq, Wk, Wv, Wo,
                                       feats_b, wq_b, wk_b, wv_b, wo_b);
    qkv_gemm<<<dim3(NPTS / 128, 3), 256, 0, stream>>>(feats_b, wq_b, wk_b, wv_b,
                                                      q8, kv8, scales4);
    attn_kernel<<<NPTS / 4, 256, 0, stream>>>(q8, kv8, scales4, knn, attn_p);
    out_gemm<<<NPTS / 128, 256, 0, stream>>>(attn_p, wo_b, bo, out);
}

// Round 5
// 50.061 us; speedup vs baseline: 1.6142x; 1.2549x over previous
//
#include <hip/hip_runtime.h>

#define NPTS 32768
#define C 128
#define KNBR 16

typedef __attribute__((ext_vector_type(8))) short short8;
typedef __attribute__((ext_vector_type(4))) float floatx4;
typedef __attribute__((ext_vector_type(4))) int intx4;

__device__ __forceinline__ ushort f2b(float f) {
    union { float f; uint u; } x; x.f = f;
    uint r = (x.u + 0x7fffu + ((x.u >> 16) & 1u)) >> 16;
    return (ushort)r;
}
__device__ __forceinline__ ushort f2h(float f) {
    union { _Float16 h; ushort u; } x; x.h = (_Float16)f; return x.u;
}
__device__ __forceinline__ float h2f(ushort u) {
    union { ushort u; _Float16 h; } x; x.u = u; return (float)x.h;
}

// int8 row permutation: byte b of word w holds channel col_of(w,b); head = w>>3 (head-pure 32B blocks)
__device__ __forceinline__ int col_of(int w, int b) {
    return 64 * (w >> 4) + 32 * ((w >> 3) & 1) + 16 * (b & 1) + 2 * (w & 7) + (b >> 1);
}

// ---------------- LDS staging (XOR-swizzled), bf16 source / fp32 source ----------------
__device__ __forceinline__ void stage128_b(const ushort* __restrict__ gsrc, ushort* lds, int tid)
{
#pragma unroll
    for (int it = 0; it < 8; ++it) {
        const int f = it * 256 + tid;
        const int row = f >> 4, slot = f & 15;
        intx4 v = *(const intx4*)(gsrc + (size_t)f * 8);
        *(intx4*)(lds + ((row * 16 + (slot ^ (row & 7))) * 8)) = v;
    }
}
__device__ __forceinline__ void stage128_f(const float* __restrict__ gsrc, ushort* lds, int tid)
{
#pragma unroll
    for (int it = 0; it < 8; ++it) {
        const int f = it * 256 + tid;
        const int row = f >> 4, slot = f & 15;
        const float* s = gsrc + (size_t)f * 8;
        float4 v0 = *(const float4*)s;
        float4 v1 = *(const float4*)(s + 4);
        intx4 o;
        o.x = (int)((uint)f2b(v0.x) | ((uint)f2b(v0.y) << 16));
        o.y = (int)((uint)f2b(v0.z) | ((uint)f2b(v0.w) << 16));
        o.z = (int)((uint)f2b(v1.x) | ((uint)f2b(v1.y) << 16));
        o.w = (int)((uint)f2b(v1.z) | ((uint)f2b(v1.w) << 16));
        *(intx4*)(lds + ((row * 16 + (slot ^ (row & 7))) * 8)) = o;
    }
}

__device__ __forceinline__ void gemm_frag_acc(const ushort* ldsA, const ushort* ldsW,
                                              floatx4 acc[4][4], int lane)
{
    const int fr = lane & 15, kb = lane >> 4;
#pragma unroll
    for (int kk = 0; kk < 4; ++kk) {
        const int slot = kk * 4 + kb;
        short8 af[4], bf[4];
#pragma unroll
        for (int i = 0; i < 4; ++i) {
            const int row = i * 16 + fr;
            af[i] = *(const short8*)(ldsA + ((row * 16 + (slot ^ (row & 7))) * 8));
            bf[i] = *(const short8*)(ldsW + ((row * 16 + (slot ^ (row & 7))) * 8));
        }
#pragma unroll
        for (int i = 0; i < 4; ++i)
#pragma unroll
            for (int j = 0; j < 4; ++j)
                acc[i][j] = __builtin_amdgcn_mfma_f32_16x16x32_bf16(af[i], bf[j], acc[i][j], 0, 0, 0);
    }
}

// QKV fused (fp32 inputs, cast in staging). grid (257, 3).
// bx==256,sel==0: permuted Wo cast. Else: sel=0 -> q8 + qscale; sel=1 -> kv8 k-half + scpack.lo;
// sel=2 -> kv8 v-half + scpack.hi. All int8 per-row-scaled, col_of-permuted.
__global__ __launch_bounds__(256) void qkv_gemm(
    const float* __restrict__ feats, const float* __restrict__ Wq,
    const float* __restrict__ Wk, const float* __restrict__ Wv,
    const float* __restrict__ Wo, ushort* __restrict__ wo_b,
    unsigned char* __restrict__ q8, unsigned char* __restrict__ kv8,
    ushort* __restrict__ scpack, float* __restrict__ qscale)
{
    const int tid = threadIdx.x;
    const int bx = blockIdx.x, sel = blockIdx.y;
    if (bx == 256) {
        if (sel != 0) return;
#pragma unroll 4
        for (int t = 0; t < 64; ++t) {
            const int gi = t * 256 + tid;
            const int j = gi >> 7, s = gi & 127;
            wo_b[gi] = f2b(Wo[(size_t)j * 128 + col_of(s >> 2, s & 3)]);
        }
        return;
    }
    __shared__ ushort ldsA[16384];
    __shared__ ushort ldsW[16384];
    __shared__ float rmax[2][128];
    const int lane = tid & 63, wid = tid >> 6;
    const int r0 = bx * 128;
    const float* W = (sel == 0) ? Wq : (sel == 1) ? Wk : Wv;

    stage128_f(feats + (size_t)r0 * 128, ldsA, tid);
    stage128_f(W, ldsW, tid);
    __syncthreads();

    floatx4 acc[4][4];
#pragma unroll
    for (int i = 0; i < 4; ++i)
#pragma unroll
        for (int j = 0; j < 4; ++j) acc[i][j] = (floatx4){0.f, 0.f, 0.f, 0.f};

    const int wr = (wid >> 1) * 64, wc = (wid & 1) * 64;
    gemm_frag_acc(ldsA + wr * 16 * 8, ldsW + wc * 16 * 8, acc, lane);

    const int fr = lane & 15, kb = lane >> 4;

    float mx[4][4];
#pragma unroll
    for (int i = 0; i < 4; ++i)
#pragma unroll
        for (int r = 0; r < 4; ++r) {
            float m = fabsf(acc[i][0][r]);
            m = fmaxf(m, fabsf(acc[i][1][r]));
            m = fmaxf(m, fabsf(acc[i][2][r]));
            m = fmaxf(m, fabsf(acc[i][3][r]));
            m = fmaxf(m, __shfl_xor(m, 1));
            m = fmaxf(m, __shfl_xor(m, 2));
            m = fmaxf(m, __shfl_xor(m, 4));
            m = fmaxf(m, __shfl_xor(m, 8));
            mx[i][r] = m;
        }
    if (fr == 0) {
#pragma unroll
        for (int i = 0; i < 4; ++i)
#pragma unroll
            for (int r = 0; r < 4; ++r)
                rmax[wc >> 6][wr + i * 16 + kb * 4 + r] = mx[i][r];
    }
    __syncthreads();

    const int boff = ((wc >> 5) + (fr & 1)) * 32 + (fr >> 1) * 4;
#pragma unroll
    for (int i = 0; i < 4; ++i)
#pragma unroll
        for (int r = 0; r < 4; ++r) {
            const int lr = wr + i * 16 + kb * 4 + r;
            const int nn = r0 + lr;
            const float comb = fmaxf(fmaxf(rmax[0][lr], rmax[1][lr]), 1e-20f);
            const float qs = 127.f / comb;
            int b0 = __float2int_rn(acc[i][0][r] * qs);
            int b1 = __float2int_rn(acc[i][1][r] * qs);
            int b2 = __float2int_rn(acc[i][2][r] * qs);
            int b3 = __float2int_rn(acc[i][3][r] * qs);
            uint u_lo = (uint)(b0 & 0xff) | ((uint)(b1 & 0xff) << 8);
            uint u_hi = (uint)(b2 & 0xff) | ((uint)(b3 & 0xff) << 8);
            uint o_lo = __shfl_xor(u_lo, 1);
            uint o_hi = __shfl_xor(u_hi, 1);
            uint word = (fr & 1) ? (o_hi | (u_hi << 16)) : (u_lo | (o_lo << 16));
            if (sel == 0) {
                *(uint*)(q8 + (size_t)nn * 128 + boff) = word;
                if (fr == 0 && wc == 0) qscale[nn] = comb * (1.f / 127.f);
            } else if (sel == 1) {
                *(uint*)(kv8 + (size_t)nn * 256 + boff) = word;
                if (fr == 0 && wc == 0) scpack[(size_t)nn * 2] = f2h(comb * (1.f / 127.f));
            } else {
                *(uint*)(kv8 + (size_t)nn * 256 + 128 + boff) = word;
                if (fr == 0 && wc == 0) scpack[(size_t)nn * 2 + 1] = f2h(comb * (1.f / 127.f));
            }
        }
}

// ---------------- attention: 1 wave/point, lane = (neighbor kk = l>>2, head h = l&3) ----------------
// Score phase: 2 dwordx4 loads/lane fetch whole wave's K; 8 sdot4, ZERO shuffles.
// Softmax: 1 exp/lane + 8 shuffle-reduce. PV: 16 one-line ushort gathers + 16 bpermutes.
__global__ __launch_bounds__(256, 6) void attn_kernel(
    const unsigned char* __restrict__ q8, const unsigned char* __restrict__ kv8,
    const ushort* __restrict__ scpack, const float* __restrict__ qscale,
    const int* __restrict__ knn, ushort* __restrict__ attn_p)
{
    const int tid = threadIdx.x;
    const int lane = tid & 63;
    const int wp = __builtin_amdgcn_readfirstlane(tid >> 6);
    const int n = blockIdx.x * 4 + wp;

    const int kk = lane >> 2, h = lane & 3;
    const int nb4 = knn[(size_t)n * KNBR + kk];     // 16 ints broadcast x4 lanes, 1 load
    const int* kr = knn + (size_t)n * KNBR;         // uniform -> scalar loads

    const unsigned char* krow = kv8 + (size_t)nb4 * 256 + h * 32;
    intx4 k0 = *(const intx4*)(krow);
    intx4 k1 = *(const intx4*)(krow + 16);
    const unsigned char* qrow = q8 + (size_t)n * 128 + h * 32;
    intx4 qq0 = *(const intx4*)(qrow);
    intx4 qq1 = *(const intx4*)(qrow + 16);
    const uint scp = *(const uint*)(scpack + (size_t)nb4 * 2);

    ushort vsh[KNBR];
#pragma unroll
    for (int j = 0; j < KNBR; ++j) {
        const int nbv = kr[j];
        vsh[j] = *(const ushort*)(kv8 + (size_t)nbv * 256 + 128 + lane * 2);
    }

    const float qs6 = qscale[n] * 0.17677669529663687f;   // qsc / sqrt(32)

    int dp = 0;
#if __has_builtin(__builtin_amdgcn_sdot4)
#pragma unroll
    for (int i = 0; i < 4; ++i) dp = __builtin_amdgcn_sdot4(qq0[i], k0[i], dp, false);
#pragma unroll
    for (int i = 0; i < 4; ++i) dp = __builtin_amdgcn_sdot4(qq1[i], k1[i], dp, false);
#else
#pragma unroll
    for (int i = 0; i < 4; ++i) {
        uint a = (uint)qq0[i], b = (uint)k0[i];
        dp += (int)(signed char)(a) * (int)(signed char)(b)
            + (int)(signed char)(a >> 8) * (int)(signed char)(b >> 8)
            + (int)(signed char)(a >> 16) * (int)(signed char)(b >> 16)
            + (int)(signed char)(a >> 24) * (int)(signed char)(b >> 24);
        a = (uint)qq1[i]; b = (uint)k1[i];
        dp += (int)(signed char)(a) * (int)(signed char)(b)
            + (int)(signed char)(a >> 8) * (int)(signed char)(b >> 8)
            + (int)(signed char)(a >> 16) * (int)(signed char)(b >> 16)
            + (int)(signed char)(a >> 24) * (int)(signed char)(b >> 24);
    }
#endif

    const float ksc = h2f((ushort)(scp & 0xffff));
    const float vsc = h2f((ushort)(scp >> 16));
    const float sc = (float)dp * ksc * qs6;

    // softmax over the 16 kk-lanes of this head (stride-4 lane group)
    float mxv = sc;
    mxv = fmaxf(mxv, __shfl_xor(mxv, 4));
    mxv = fmaxf(mxv, __shfl_xor(mxv, 8));
    mxv = fmaxf(mxv, __shfl_xor(mxv, 16));
    mxv = fmaxf(mxv, __shfl_xor(mxv, 32));
    const float e = __expf(sc - mxv);
    float sm = e;
    sm += __shfl_xor(sm, 4);
    sm += __shfl_xor(sm, 8);
    sm += __shfl_xor(sm, 16);
    sm += __shfl_xor(sm, 32);
    const float wgt = e * vsc / sm;     // vsc and 1/sum folded in before broadcast

    // PV: lane covers v-half bytes {2l, 2l+1} -> head l>>4
    const int h2v = lane >> 4;
    float a0 = 0.f, a1 = 0.f;
#pragma unroll
    for (int j = 0; j < KNBR; ++j) {
        const float w2 = __shfl(wgt, j * 4 + h2v);
        const ushort u = vsh[j];
        a0 += w2 * (float)(signed char)(u & 0xff);
        a1 += w2 * (float)(signed char)(u >> 8);
    }
    const uint pr = (uint)f2b(a0) | ((uint)f2b(a1) << 16);
    *(uint*)(attn_p + (size_t)n * 128 + lane * 2) = pr;
}

// Output projection: out = attn_p @ wo_b^T + bo (shared col_of K-permutation)
__global__ __launch_bounds__(256) void out_gemm(
    const ushort* __restrict__ A, const ushort* __restrict__ Wo_b,
    const float* __restrict__ bias, float* __restrict__ out)
{
    __shared__ ushort ldsA[16384];
    __shared__ ushort ldsW[16384];
    const int tid = threadIdx.x, lane = tid & 63, wid = tid >> 6;
    const int r0 = blockIdx.x * 128;

    stage128_b(A + (size_t)r0 * 128, ldsA, tid);
    stage128_b(Wo_b, ldsW, tid);
    __syncthreads();

    floatx4 acc[4][4];
#pragma unroll
    for (int i = 0; i < 4; ++i)
#pragma unroll
        for (int j = 0; j < 4; ++j) acc[i][j] = (floatx4){0.f, 0.f, 0.f, 0.f};

    const int wr = (wid >> 1) * 64, wc = (wid & 1) * 64;
    gemm_frag_acc(ldsA + wr * 16 * 8, ldsW + wc * 16 * 8, acc, lane);

    const int fr = lane & 15, kb = lane >> 4;
#pragma unroll
    for (int i = 0; i < 4; ++i)
#pragma unroll
        for (int j = 0; j < 4; ++j) {
            const int col = wc + j * 16 + fr;
            const float bv = bias[col];
#pragma unroll
            for (int r = 0; r < 4; ++r) {
                const int n = r0 + wr + i * 16 + kb * 4 + r;
                out[(size_t)n * 128 + col] = acc[i][j][r] + bv;
            }
        }
}

extern "C" void kernel_launch(void* const* d_in, const int* in_sizes, int n_in,
                              void* d_out, int out_size, void* d_ws, size_t ws_size,
                              hipStream_t stream)
{
    const float* feats = (const float*)d_in[0];
    const int*   knn   = (const int*)d_in[2];
    const float* Wq    = (const float*)d_in[3];
    const float* Wk    = (const float*)d_in[4];
    const float* Wv    = (const float*)d_in[5];
    const float* Wo    = (const float*)d_in[6];
    const float* bo    = (const float*)d_in[7];
    float* out = (float*)d_out;

    ushort* attn_p = (ushort*)d_ws;                                    // N*128 ushort (8 MB)
    unsigned char* q8  = (unsigned char*)(attn_p + (size_t)NPTS * C);  // N*128 B
    unsigned char* kv8 = q8 + (size_t)NPTS * 128;                      // N*256 B
    ushort* scpack = (ushort*)(kv8 + (size_t)NPTS * 256);              // N*2 ushort
    float* qscale  = (float*)(scpack + (size_t)NPTS * 2);              // N floats
    ushort* wo_b   = (ushort*)(qscale + (size_t)NPTS);                 // 16384 ushort

    qkv_gemm<<<dim3(257, 3), 256, 0, stream>>>(feats, Wq, Wk, Wv, Wo, wo_b,
                                               q8, kv8, scpack, qscale);
    attn_kernel<<<NPTS / 4, 256, 0, stream>>>(q8, kv8, scpack, qscale, knn, attn_p);
    out_gemm<<<NPTS / 128, 256, 0, stream>>>(attn_p, wo_b, bo, out);
}